// Round 8
// baseline (133.436 us; speedup 1.0000x reference)
//
#include <hip/hip_runtime.h>

#define KTAG 52
#define START_TAG 50
#define STOP_TAG 51
#define TMAX 512
#define NCU 256

__device__ __forceinline__ float rdlanef(float v, int l) {
    return __int_as_float(__builtin_amdgcn_readlane(__float_as_int(v), l));
}

// Scaled linear-domain chain. beta broadcast via per-wave-private LDS region:
// 1 ds_write + 13 uniform-address ds_read_b128 (broadcast, conflict-free).
// NO barrier inside the loop: same-wave write->read ordering is lgkmcnt,
// which never drains the vmcnt logit prefetch.
// FWD:  beta' = matv(E, beta) * e_t        BWD:  beta' = matv(E^T, beta * e_t)
template<bool BWD>
__device__ __forceinline__ float chain(const float* __restrict__ p0, int stride,
                                       int maxk, int nsteps,
                                       const float* __restrict__ Erow,
                                       float* sb, int lane,
                                       float beta, float& M2) {
    constexpr float L2E = 1.4426950408889634f;
    M2 = 0.f;

    auto lgt = [&](int k) -> float {
        int kc = k < maxk ? k : maxk;          // clamped prefetch, always in-bounds
        return p0[(long)stride * kc];
    };
    auto STEP = [&](float lg, float scl) {
        float e = exp2f(lg * L2E);
        float x = beta * scl;
        if (BWD) x *= e;
        sb[lane] = x;                          // compiler inserts lgkmcnt wait
        float a0 = 0.f, a1 = 0.f, a2 = 0.f, a3 = 0.f;
        #pragma unroll
        for (int p = 0; p < 13; ++p) {
            float4 bv = *reinterpret_cast<const float4*>(&sb[4 * p]);
            a0 = fmaf(Erow[4*p+0], bv.x, a0);
            a1 = fmaf(Erow[4*p+1], bv.y, a1);
            a2 = fmaf(Erow[4*p+2], bv.z, a2);
            a3 = fmaf(Erow[4*p+3], bv.w, a3);
        }
        float r = (a0 + a1) + (a2 + a3);
        beta = BWD ? r : r * e;
    };

    float l0 = lgt(0), l1 = lgt(1), l2 = lgt(2), l3 = lgt(3);
    int k = 0;
    while (k + 4 <= nsteps) {
        float n0 = lgt(k+4), n1 = lgt(k+5), n2 = lgt(k+6), n3 = lgt(k+7);
        float scl = 1.f;
        if (k > 0) {                            // uniform; beta[0] > 0 once started
            float m = fmaxf(rdlanef(beta, 0), 1e-30f);
            M2 += log2f(m);
            scl = 1.f / m;
        }
        STEP(l0, scl); STEP(l1, 1.f); STEP(l2, 1.f); STEP(l3, 1.f);
        l0 = n0; l1 = n1; l2 = n2; l3 = n3;
        k += 4;
    }
    if (k < nsteps) {
        float scl = 1.f;
        if (k > 0) {
            float m = fmaxf(rdlanef(beta, 0), 1e-30f);
            M2 += log2f(m);
            scl = 1.f / m;
        }
        STEP(l0, scl); ++k;
        if (k < nsteps) { STEP(l1, 1.f); ++k; }
        if (k < nsteps) { STEP(l2, 1.f); ++k; }
    }
    return beta;
}

// ---- Deterministic length-rank: perm[rank] = b (ascending len, idx tiebreak)
// Uniform Lb via one vector load + __shfl broadcast (no serial scalar loads).
#define LPL 16
__global__ __launch_bounds__(64) void rank_kernel(
    const int* __restrict__ lens, int* __restrict__ perm, int B)
{
    const int lane = threadIdx.x;
    int myl[LPL];
    #pragma unroll
    for (int k = 0; k < LPL; ++k) {
        int j = lane * LPL + k;
        myl[k] = (j < B) ? lens[j] : 0x7fffffff;
    }
    const int base = blockIdx.x * 64;
    const int Lme = (base + lane < B) ? lens[base + lane] : 0x7fffffff;
    for (int i = 0; i < 64; ++i) {
        int b = base + i;
        if (b >= B) break;
        int Lb = __shfl(Lme, i);               // broadcast, no global load
        int r = 0;
        #pragma unroll
        for (int k = 0; k < LPL; ++k) {
            int j = lane * LPL + k;
            r += (myl[k] < Lb || (myl[k] == Lb && j < b)) ? 1 : 0;
        }
        #pragma unroll
        for (int off = 32; off; off >>= 1) r += __shfl_xor(r, off);
        if (lane == 0) perm[r] = b;
    }
}

// One block (2 waves) per batch: wave0 fwd half, wave1 bwd half; combine after
// ONE barrier (outside all loops). CU c's four co-resident blocks map to ranks
// {2c, 2c+1, 1022-2c, 1023-2c}: two EQUAL-length pairs, so co-resident waves
// issue-share for their whole lifetime; per-CU total work constant.
__global__ __launch_bounds__(128, 1) void crf_split_kernel(
    const float* __restrict__ logits,   // [B, T, K]
    const float* __restrict__ trans,    // [K, K]
    const int*   __restrict__ labels,   // [B, T]
    const int*   __restrict__ lens,     // [B]
    const int*   __restrict__ perm,     // [B]
    float* __restrict__ out, int B)
{
    constexpr float L2E = 1.4426950408889634f;
    constexpr float LN2 = 0.6931471805599453f;

    const int blk  = blockIdx.x;
    const int wave = threadIdx.x >> 6;
    const int lane = threadIdx.x & 63;
    const bool active = lane < KTAG;
    const bool bwd = (wave == 1);

    int r = blk;
    if (B == 4 * NCU) {
        int q = blk & (NCU - 1), j = blk >> 8;
        r = (j == 0) ? (2 * q)
          : (j == 1) ? (2 * q + 1)
          : (j == 2) ? (1022 - 2 * q)
          :            (1023 - 2 * q);
    }
    const int batch = perm[r];
    const int len = lens[batch];
    const int mid = len >> 1;               // fwd steps; bwd = len - mid >= 1

    // E row: wave0 = exp(trans[lane][j]) (row), wave1 = exp(trans[j][lane]) (col)
    float Erow[KTAG];
    #pragma unroll
    for (int j = 0; j < KTAG; ++j) {
        float tv = active ? (bwd ? trans[j * KTAG + lane]
                                 : trans[(size_t)lane * KTAG + j]) : 0.f;
        Erow[j] = active ? exp2f(tv * L2E) : 0.f;
    }

    const float* base = logits + (size_t)batch * TMAX * KTAG + (active ? lane : 0);

    __shared__ __align__(16) float sbeta[2][64];   // per-wave private scratch
    __shared__ float sM2f, sEm, sTr;

    float M2, beta;
    if (bwd) {
        float b0 = active ? exp2f(trans[STOP_TAG * KTAG + lane] * L2E) : 0.f;
        beta = chain<true>(base + (size_t)(len - 1) * KTAG, -KTAG,
                           len - 1, len - mid, Erow, &sbeta[1][0], lane, b0, M2);
    } else {
        float b0 = (lane == START_TAG) ? 1.f : 0.f;
        beta = chain<false>(base, KTAG, TMAX - 1, mid, Erow,
                            &sbeta[0][0], lane, b0, M2);

        // gold-path scores on the (shorter) fwd wave; batched independent loads
        const int*   labp = labels + (size_t)batch * TMAX;
        const float* lgb  = logits + (size_t)batch * TMAX * KTAG;
        int lab[8], prv[8]; bool msk[8];
        #pragma unroll
        for (int c = 0; c < 8; ++c) {
            int tt = c * 64 + lane;
            msk[c] = tt < len;
            int ttc = msk[c] ? tt : 0;
            lab[c] = labp[ttc];
            prv[c] = (ttc == 0) ? START_TAG : labp[ttc - 1];
        }
        float em = 0.f, tr = 0.f;
        #pragma unroll
        for (int c = 0; c < 8; ++c) {
            int ttc = msk[c] ? (c * 64 + lane) : 0;
            float ev = lgb[(size_t)ttc * KTAG + lab[c]];
            float tv = trans[lab[c] * KTAG + prv[c]];
            if (msk[c]) { em += ev; tr += tv; }
        }
        if (lane == 0) tr += trans[STOP_TAG * KTAG + labp[len - 1]];
        #pragma unroll
        for (int off = 32; off; off >>= 1) {
            em += __shfl_xor(em, off);
            tr += __shfl_xor(tr, off);
        }
        sbeta[0][lane] = beta;                // final fwd state for the combine
        if (lane == 0) { sM2f = M2; sEm = em; sTr = tr; }
    }
    __syncthreads();                          // single barrier, outside all loops

    if (bwd) {
        // Z = gamma^T beta_mid
        float d = beta * sbeta[0][lane];
        #pragma unroll
        for (int off = 32; off; off >>= 1) d += __shfl_xor(d, off);
        float partition = LN2 * (sM2f + M2 + log2f(d));
        if (lane == 0) out[batch] = partition + sEm - sTr;
    }
}

extern "C" void kernel_launch(void* const* d_in, const int* in_sizes, int n_in,
                              void* d_out, int out_size, void* d_ws, size_t ws_size,
                              hipStream_t stream) {
    const float* logits = (const float*)d_in[0];
    const float* trans  = (const float*)d_in[1];
    const int*   labels = (const int*)d_in[2];
    const int*   lens   = (const int*)d_in[3];
    float* out = (float*)d_out;

    const int B = in_sizes[3];
    int* perm = (int*)d_ws;

    rank_kernel<<<dim3((B + 63) / 64), dim3(64), 0, stream>>>(lens, perm, B);
    crf_split_kernel<<<dim3(B), dim3(128), 0, stream>>>(
        logits, trans, labels, lens, perm, out, B);
}

// Round 9
// 119.288 us; speedup vs baseline: 1.1186x; 1.1186x over previous
//
#include <hip/hip_runtime.h>

#define KTAG 52
#define START_TAG 50
#define STOP_TAG 51
#define TMAX 512

__device__ __forceinline__ float rdlanef(float v, int l) {
    return __int_as_float(__builtin_amdgcn_readlane(__float_as_int(v), l));
}

// One wave per batch. Forward chain (mid steps, E) and backward chain
// (len-mid steps, E^T) of the SAME batch run interleaved in one wave:
// each chain's readlane/dep stalls are filled by the other chain's issue.
// No LDS, no barriers anywhere. Combine via shuffle at the end.
__global__ __launch_bounds__(64, 1) void crf_fused_kernel(
    const float* __restrict__ logits,   // [B, T, K]
    const float* __restrict__ trans,    // [K, K]  trans[to][from]
    const int*   __restrict__ labels,   // [B, T]
    const int*   __restrict__ lens,     // [B]
    float* __restrict__ out)            // [B]
{
    constexpr float L2E = 1.4426950408889634f;
    constexpr float LN2 = 0.6931471805599453f;

    const int b    = blockIdx.x;
    const int lane = threadIdx.x;
    const bool active = lane < KTAG;
    const int len = lens[b];                 // >= 1
    const int mid = len >> 1;                // fwd steps; bwd steps = len - mid

    // EF[j] = exp(trans[lane][j])  (fwd row);  EB[j] = exp(trans[j][lane]) (E^T row)
    float EF[KTAG], EB[KTAG];
    #pragma unroll
    for (int j = 0; j < KTAG; ++j) {
        float tf = active ? trans[(size_t)lane * KTAG + j] : 0.f;
        float tb = active ? trans[(size_t)j * KTAG + lane] : 0.f;
        EF[j] = active ? exp2f(tf * L2E) : 0.f;
        EB[j] = active ? exp2f(tb * L2E) : 0.f;
    }

    const float* pF = logits + (size_t)b * TMAX * KTAG + (active ? lane : 0);
    const float* pB = pF + (size_t)(len - 1) * KTAG;

    auto lgF = [&](int k) -> float {         // fwd logit t=k (clamped, in-bounds)
        int kc = k < TMAX - 1 ? k : TMAX - 1;
        return pF[(long)KTAG * kc];
    };
    auto lgB = [&](int k) -> float {         // bwd logit t=len-1-k (clamped)
        int kc = k < len - 1 ? k : len - 1;
        return pB[-(long)KTAG * kc];
    };

    float betaF = (lane == START_TAG) ? 1.f : 0.f;                       // fwd state
    float gamma = active ? exp2f(trans[STOP_TAG * KTAG + lane] * L2E) : 0.f; // bwd state
    float M2F = 0.f, M2B = 0.f;

    // one fwd + one bwd step, interleaved at 4-element granularity
    auto STEP2 = [&](float lf, float sf, float lb, float sb) {
        float eF = exp2f(lf * L2E);
        float eB = exp2f(lb * L2E);
        float xF = betaF * sf;
        float xB = gamma * sb * eB;
        float fa0 = 0.f, fa1 = 0.f, fa2 = 0.f, fa3 = 0.f;
        float ba0 = 0.f, ba1 = 0.f, ba2 = 0.f, ba3 = 0.f;
        #pragma unroll
        for (int p = 0; p < 13; ++p) {
            fa0 = fmaf(EF[4*p+0], rdlanef(xF, 4*p+0), fa0);
            ba0 = fmaf(EB[4*p+0], rdlanef(xB, 4*p+0), ba0);
            fa1 = fmaf(EF[4*p+1], rdlanef(xF, 4*p+1), fa1);
            ba1 = fmaf(EB[4*p+1], rdlanef(xB, 4*p+1), ba1);
            fa2 = fmaf(EF[4*p+2], rdlanef(xF, 4*p+2), fa2);
            ba2 = fmaf(EB[4*p+2], rdlanef(xB, 4*p+2), ba2);
            fa3 = fmaf(EF[4*p+3], rdlanef(xF, 4*p+3), fa3);
            ba3 = fmaf(EB[4*p+3], rdlanef(xB, 4*p+3), ba3);
        }
        betaF = ((fa0 + fa1) + (fa2 + fa3)) * eF;
        gamma = ((ba0 + ba1) + (ba2 + ba3));
    };
    auto STEPB = [&](float lb, float sb) {   // solo bwd step (odd-len tail)
        float eB = exp2f(lb * L2E);
        float xB = gamma * sb * eB;
        float a0 = 0.f, a1 = 0.f, a2 = 0.f, a3 = 0.f;
        #pragma unroll
        for (int p = 0; p < 13; ++p) {
            a0 = fmaf(EB[4*p+0], rdlanef(xB, 4*p+0), a0);
            a1 = fmaf(EB[4*p+1], rdlanef(xB, 4*p+1), a1);
            a2 = fmaf(EB[4*p+2], rdlanef(xB, 4*p+2), a2);
            a3 = fmaf(EB[4*p+3], rdlanef(xB, 4*p+3), a3);
        }
        gamma = (a0 + a1) + (a2 + a3);
    };

    // depth-4 rolling prefetch per chain
    float f0 = lgF(0), f1 = lgF(1), f2 = lgF(2), f3 = lgF(3);
    float g0 = lgB(0), g1 = lgB(1), g2 = lgB(2), g3 = lgB(3);

    int t = 0;
    while (t + 4 <= mid) {
        float nf0 = lgF(t+4), nf1 = lgF(t+5), nf2 = lgF(t+6), nf3 = lgF(t+7);
        float ng0 = lgB(t+4), ng1 = lgB(t+5), ng2 = lgB(t+6), ng3 = lgB(t+7);
        float sF = 1.f, sB = 1.f;
        if (t > 0) {                         // uniform; states > 0 once started
            float mF = fmaxf(rdlanef(betaF, 0), 1e-30f);
            float mB = fmaxf(rdlanef(gamma, 0), 1e-30f);
            M2F += log2f(mF); sF = 1.f / mF;
            M2B += log2f(mB); sB = 1.f / mB;
        }
        STEP2(f0, sF, g0, sB);
        STEP2(f1, 1.f, g1, 1.f);
        STEP2(f2, 1.f, g2, 1.f);
        STEP2(f3, 1.f, g3, 1.f);
        f0 = nf0; f1 = nf1; f2 = nf2; f3 = nf3;
        g0 = ng0; g1 = ng1; g2 = ng2; g3 = ng3;
        t += 4;
    }
    const int r = mid - t;                   // 0..3 paired remainder
    if (r > 0) {
        float sF = 1.f, sB = 1.f;
        if (t > 0) {
            float mF = fmaxf(rdlanef(betaF, 0), 1e-30f);
            float mB = fmaxf(rdlanef(gamma, 0), 1e-30f);
            M2F += log2f(mF); sF = 1.f / mF;
            M2B += log2f(mB); sB = 1.f / mB;
        }
        STEP2(f0, sF, g0, sB);
        if (r > 1) STEP2(f1, 1.f, g1, 1.f);
        if (r > 2) STEP2(f2, 1.f, g2, 1.f);
    }
    if (len - mid > mid) {                   // odd len: one extra bwd step
        float gl = (r == 0) ? g0 : (r == 1) ? g1 : (r == 2) ? g2 : g3;
        STEPB(gl, 1.f);
    }

    // ---- combine: Z = gamma^T betaF ----
    float d = gamma * betaF;
    #pragma unroll
    for (int off = 32; off; off >>= 1) d += __shfl_xor(d, off);
    float partition = LN2 * (M2F + M2B + log2f(d));

    // ---- gold-path scores (t-parallel, batched independent loads) ----
    const int*   labp = labels + (size_t)b * TMAX;
    const float* lgb  = logits + (size_t)b * TMAX * KTAG;
    int lab[8], prv[8]; bool msk[8];
    #pragma unroll
    for (int c = 0; c < 8; ++c) {
        int tt = c * 64 + lane;
        msk[c] = tt < len;
        int ttc = msk[c] ? tt : 0;
        lab[c] = labp[ttc];
        prv[c] = (ttc == 0) ? START_TAG : labp[ttc - 1];
    }
    float em = 0.f, tr = 0.f;
    #pragma unroll
    for (int c = 0; c < 8; ++c) {
        int ttc = msk[c] ? (c * 64 + lane) : 0;
        float ev = lgb[(size_t)ttc * KTAG + lab[c]];
        float tv = trans[lab[c] * KTAG + prv[c]];
        if (msk[c]) { em += ev; tr += tv; }
    }
    if (lane == 0) tr += trans[STOP_TAG * KTAG + labp[len - 1]];
    #pragma unroll
    for (int off = 32; off; off >>= 1) {
        em += __shfl_xor(em, off);
        tr += __shfl_xor(tr, off);
    }

    if (lane == 0) out[b] = partition + em - tr;
}

extern "C" void kernel_launch(void* const* d_in, const int* in_sizes, int n_in,
                              void* d_out, int out_size, void* d_ws, size_t ws_size,
                              hipStream_t stream) {
    const float* logits = (const float*)d_in[0];
    const float* trans  = (const float*)d_in[1];
    const int*   labels = (const int*)d_in[2];
    const int*   lens   = (const int*)d_in[3];
    float* out = (float*)d_out;

    const int B = in_sizes[3];
    crf_fused_kernel<<<dim3(B), dim3(64), 0, stream>>>(logits, trans, labels, lens, out);
}